// Round 1
// baseline (558.009 us; speedup 1.0000x reference)
//
#include <hip/hip_runtime.h>
#include <hip/hip_bf16.h>

typedef __bf16 bf16x8 __attribute__((ext_vector_type(8)));
typedef float f32x4 __attribute__((ext_vector_type(4)));

// ---- problem constants ----
// B=4, S=2048, E=1024, H=16, D=64
// ws layout (bf16 element offsets)
constexpr size_t XQ_OFF = 0;                 // x_q bf16 [8192][1024]
constexpr size_t XK_OFF = 8388608;
constexpr size_t XV_OFF = 16777216;
constexpr size_t WQ_OFF = 25165824;          // W bf16 [1024][1024] (row-major = [N][K])
constexpr size_t WK_OFF = 26214400;
constexpr size_t WV_OFF = 27262976;
constexpr size_t WO_OFF = 28311552;
constexpr size_t Q_OFF  = 29360128;          // Q bf16 [bh][s][d]
constexpr size_t KK_OFF = 37748736;          // K bf16 [bh][s][d]
constexpr size_t VT_OFF = 46137344;          // V^T bf16 [bh][d][s]
constexpr size_t CTX_OFF= 54525952;          // ctx merged bf16 [8192][1024]

__device__ __forceinline__ void gload16(const void* g, void* s) {
    __builtin_amdgcn_global_load_lds((__attribute__((address_space(1))) void*)g,
                                     (__attribute__((address_space(3))) void*)s, 16, 0, 0);
}

// ---------------- convert fp32 -> bf16 into ws ----------------
__global__ __launch_bounds__(256) void convert_k(
    const float* __restrict__ q, const float* __restrict__ k, const float* __restrict__ v,
    const float* __restrict__ Wq, const float* __restrict__ Wk, const float* __restrict__ Wv,
    const float* __restrict__ Wo, __bf16* __restrict__ ws) {
    int id = blockIdx.x * 256 + threadIdx.x;     // one 8-elem chunk per thread
    const int NX = 1048576;                      // chunks per X (8388608/8)
    const int NW = 131072;                       // chunks per W (1048576/8)
    const float* src; size_t dst; int local;
    if (id < 3 * NX) {
        int z = id / NX; local = id - z * NX;
        src = (z == 0) ? q : ((z == 1) ? k : v);
        dst = XQ_OFF + (size_t)z * 8388608;
    } else {
        int i2 = id - 3 * NX;
        int z = i2 / NW; local = i2 - z * NW;
        src = (z == 0) ? Wq : ((z == 1) ? Wk : ((z == 2) ? Wv : Wo));
        dst = WQ_OFF + (size_t)z * 1048576;
    }
    const float4* s4 = (const float4*)(src + (size_t)local * 8);
    float4 a = s4[0], b = s4[1];
    bf16x8 o;
    o[0]=(__bf16)a.x; o[1]=(__bf16)a.y; o[2]=(__bf16)a.z; o[3]=(__bf16)a.w;
    o[4]=(__bf16)b.x; o[5]=(__bf16)b.y; o[6]=(__bf16)b.z; o[7]=(__bf16)b.w;
    *(bf16x8*)(ws + dst + (size_t)local * 8) = o;
}

// ---------------- GEMM  C = A @ B^T (+bias), m97-style 128x128/BK32 ----------------
// MODE 0: z in {0,1,2} -> Q/K/V projection; writes Q,K as [bh][s][d] bf16, V as [bh][d][s] bf16
// MODE 1: out projection; writes fp32 d_out
template<int MODE>
__global__ __launch_bounds__(256) void gemm_k(
    __bf16* __restrict__ ws,
    const float* __restrict__ bq, const float* __restrict__ bk,
    const float* __restrict__ bv, const float* __restrict__ bo,
    float* __restrict__ out) {
    const int K = 1024;
    int z = blockIdx.z;
    const __bf16* A; const __bf16* Bm; const float* bias;
    if (MODE == 0) {
        A    = ws + XQ_OFF + (size_t)z * 8388608;
        Bm   = ws + WQ_OFF + (size_t)z * 1048576;
        bias = (z == 0) ? bq : ((z == 1) ? bk : bv);
    } else {
        A    = ws + CTX_OFF;
        Bm   = ws + WO_OFF;
        bias = bo;
    }
    int row0 = blockIdx.x * 128, col0 = blockIdx.y * 128;
    __shared__ __align__(16) __bf16 As[128 * 32];
    __shared__ __align__(16) __bf16 Bs[128 * 32];
    int t = threadIdx.x, lane = t & 63, w = t >> 6;
    int wr = w >> 1, wc = w & 1;
    f32x4 acc[4][4];
#pragma unroll
    for (int i = 0; i < 4; ++i)
#pragma unroll
        for (int j = 0; j < 4; ++j) acc[i][j] = (f32x4){0.f, 0.f, 0.f, 0.f};

    for (int kt = 0; kt < K; kt += 32) {
#pragma unroll
        for (int i = 0; i < 2; ++i) {
            int e = ((i * 4 + w) * 64 + lane) * 8;   // elem offset in [128][32] tile
            int r = e >> 5, c = e & 31;
            gload16(A  + (size_t)(row0 + r) * K + kt + c, As + e);
            gload16(Bm + (size_t)(col0 + r) * K + kt + c, Bs + e);
        }
        __syncthreads();
        bf16x8 af[4], bfr[4];
#pragma unroll
        for (int f = 0; f < 4; ++f) {
            af[f]  = *(const bf16x8*)&As[(wr * 64 + f * 16 + (lane & 15)) * 32 + (lane >> 4) * 8];
            bfr[f] = *(const bf16x8*)&Bs[(wc * 64 + f * 16 + (lane & 15)) * 32 + (lane >> 4) * 8];
        }
#pragma unroll
        for (int fr = 0; fr < 4; ++fr)
#pragma unroll
            for (int fc = 0; fc < 4; ++fc)
                acc[fr][fc] = __builtin_amdgcn_mfma_f32_16x16x32_bf16(af[fr], bfr[fc], acc[fr][fc], 0, 0, 0);
        __syncthreads();
    }

    // epilogue
    if (MODE == 0) {
        __bf16* dqk = ws + Q_OFF + (size_t)z * 8388608;  // z=0 -> Q, z=1 -> K
        __bf16* dvt = ws + VT_OFF;
#pragma unroll
        for (int fr = 0; fr < 4; ++fr)
#pragma unroll
            for (int fc = 0; fc < 4; ++fc)
#pragma unroll
                for (int r = 0; r < 4; ++r) {
                    int m = row0 + wr * 64 + fr * 16 + ((lane >> 4) << 2) + r;
                    int n = col0 + wc * 64 + fc * 16 + (lane & 15);
                    float val = acc[fr][fc][r] + bias[n];
                    int bb = m >> 11, s = m & 2047, h = n >> 6, d = n & 63;
                    size_t bh = (size_t)bb * 16 + h;
                    if (z < 2) dqk[bh * 131072 + (size_t)s * 64 + d] = (__bf16)val;
                    else       dvt[bh * 131072 + (size_t)d * 2048 + s] = (__bf16)val;
                }
    } else {
#pragma unroll
        for (int fr = 0; fr < 4; ++fr)
#pragma unroll
            for (int fc = 0; fc < 4; ++fc)
#pragma unroll
                for (int r = 0; r < 4; ++r) {
                    int m = row0 + wr * 64 + fr * 16 + ((lane >> 4) << 2) + r;
                    int n = col0 + wc * 64 + fc * 16 + (lane & 15);
                    out[(size_t)m * 1024 + n] = acc[fr][fc][r] + bias[n];
                }
    }
}

// ---------------- fused attention (two-pass, no-max softmax) ----------------
// block: (q-tile of 64 rows) x (one bh); 256 threads = 4 waves, wave w owns q rows [w*16, w*16+16)
__global__ __launch_bounds__(256) void attn_k(const __bf16* __restrict__ ws,
                                              __bf16* __restrict__ wsw,
                                              float* __restrict__ wout) {
    const __bf16* Qp  = ws + Q_OFF;
    const __bf16* Kp  = ws + KK_OFF;
    const __bf16* Vtp = ws + VT_OFF;
    __bf16* ctx = wsw + CTX_OFF;

    int bh = blockIdx.y;            // 0..63
    int q0 = blockIdx.x * 64;       // 0..2047
    int t = threadIdx.x, lane = t & 63, w = t >> 6;
    __shared__ __align__(16) __bf16 Qs[64 * 64];
    __shared__ __align__(16) __bf16 Ks[64 * 64];
    __shared__ __align__(16) __bf16 Vts[64 * 64];
    __shared__ __align__(16) __bf16 Ps[64 * 64];
    const float SCALE = 0.125f;

    // stage Q (swizzled: byte ^= (row&7)<<4 within 128B row)
#pragma unroll
    for (int i = 0; i < 2; ++i) {
        int ch = t + 256 * i;
        int r = ch >> 3, c8 = ch & 7;
        bf16x8 val = *(const bf16x8*)&Qp[(size_t)bh * 131072 + (size_t)(q0 + r) * 64 + c8 * 8];
        *(bf16x8*)((char*)Qs + (r * 128 + ((c8 * 16) ^ ((r & 7) << 4)))) = val;
    }
    __syncthreads();
    int qrow = w * 16 + (lane & 15);
    bf16x8 aq0 = *(const bf16x8*)((char*)Qs + (qrow * 128 + (((lane >> 4) * 16)      ^ ((qrow & 7) << 4))));
    bf16x8 aq1 = *(const bf16x8*)((char*)Qs + (qrow * 128 + ((64 + (lane >> 4) * 16) ^ ((qrow & 7) << 4))));

    // ---- pass 1: row sums of exp(score) ----
    float rs[4] = {0.f, 0.f, 0.f, 0.f};
    for (int kt = 0; kt < 2048; kt += 64) {
        __syncthreads();
#pragma unroll
        for (int i = 0; i < 2; ++i) {
            int ch = t + 256 * i; int r = ch >> 3, c8 = ch & 7;
            bf16x8 val = *(const bf16x8*)&Kp[(size_t)bh * 131072 + (size_t)(kt + r) * 64 + c8 * 8];
            *(bf16x8*)((char*)Ks + (r * 128 + ((c8 * 16) ^ ((r & 7) << 4)))) = val;
        }
        __syncthreads();
#pragma unroll
        for (int kc = 0; kc < 4; ++kc) {
            int krow = kc * 16 + (lane & 15);
            bf16x8 b0 = *(const bf16x8*)((char*)Ks + (krow * 128 + (((lane >> 4) * 16)      ^ ((krow & 7) << 4))));
            bf16x8 b1 = *(const bf16x8*)((char*)Ks + (krow * 128 + ((64 + (lane >> 4) * 16) ^ ((krow & 7) << 4))));
            f32x4 s = (f32x4){0.f, 0.f, 0.f, 0.f};
            s = __builtin_amdgcn_mfma_f32_16x16x32_bf16(aq0, b0, s, 0, 0, 0);
            s = __builtin_amdgcn_mfma_f32_16x16x32_bf16(aq1, b1, s, 0, 0, 0);
#pragma unroll
            for (int r = 0; r < 4; ++r) rs[r] += __expf(s[r] * SCALE);
        }
    }
#pragma unroll
    for (int m = 1; m < 16; m <<= 1)
#pragma unroll
        for (int r = 0; r < 4; ++r) rs[r] += __shfl_xor(rs[r], m, 64);
    float rinv[4];
#pragma unroll
    for (int r = 0; r < 4; ++r) rinv[r] = 1.f / rs[r];

    // ---- pass 2: weights write + P@V ----
    f32x4 cacc[4];
#pragma unroll
    for (int i = 0; i < 4; ++i) cacc[i] = (f32x4){0.f, 0.f, 0.f, 0.f};

    for (int kt = 0; kt < 2048; kt += 64) {
        __syncthreads();
#pragma unroll
        for (int i = 0; i < 2; ++i) {
            int ch = t + 256 * i; int r = ch >> 3, c8 = ch & 7;
            bf16x8 kv = *(const bf16x8*)&Kp[(size_t)bh * 131072 + (size_t)(kt + r) * 64 + c8 * 8];
            *(bf16x8*)((char*)Ks + (r * 128 + ((c8 * 16) ^ ((r & 7) << 4)))) = kv;
            bf16x8 vv = *(const bf16x8*)&Vtp[(size_t)bh * 131072 + (size_t)r * 2048 + kt + c8 * 8];
            *(bf16x8*)((char*)Vts + (r * 128 + ((c8 * 16) ^ ((r & 7) << 4)))) = vv;
        }
        __syncthreads();
#pragma unroll
        for (int kc = 0; kc < 4; ++kc) {
            int krow = kc * 16 + (lane & 15);
            bf16x8 b0 = *(const bf16x8*)((char*)Ks + (krow * 128 + (((lane >> 4) * 16)      ^ ((krow & 7) << 4))));
            bf16x8 b1 = *(const bf16x8*)((char*)Ks + (krow * 128 + ((64 + (lane >> 4) * 16) ^ ((krow & 7) << 4))));
            f32x4 s = (f32x4){0.f, 0.f, 0.f, 0.f};
            s = __builtin_amdgcn_mfma_f32_16x16x32_bf16(aq0, b0, s, 0, 0, 0);
            s = __builtin_amdgcn_mfma_f32_16x16x32_bf16(aq1, b1, s, 0, 0, 0);
            float e[4];
#pragma unroll
            for (int r = 0; r < 4; ++r) e[r] = __expf(s[r] * SCALE) * rinv[r];
            size_t wbase = ((size_t)bh * 2048 + q0 + w * 16 + ((lane >> 4) << 2)) * 2048
                           + kt + kc * 16 + (lane & 15);
#pragma unroll
            for (int r = 0; r < 4; ++r) wout[wbase + (size_t)r * 2048] = e[r];
#pragma unroll
            for (int r = 0; r < 4; ++r) {
                int prow = w * 16 + ((lane >> 4) << 2) + r;
                int pcol = kc * 16 + (lane & 15);
                *(__bf16*)((char*)Ps + (prow * 128 + ((pcol * 2) ^ ((prow & 7) << 4)))) = (__bf16)e[r];
            }
        }
        __syncthreads();
#pragma unroll
        for (int ks = 0; ks < 2; ++ks) {
            int arow = w * 16 + (lane & 15);
            bf16x8 ap = *(const bf16x8*)((char*)Ps + (arow * 128 + ((ks * 64 + (lane >> 4) * 16) ^ ((arow & 7) << 4))));
#pragma unroll
            for (int dc = 0; dc < 4; ++dc) {
                int vrow = dc * 16 + (lane & 15);
                bf16x8 bv = *(const bf16x8*)((char*)Vts + (vrow * 128 + ((ks * 64 + (lane >> 4) * 16) ^ ((vrow & 7) << 4))));
                cacc[dc] = __builtin_amdgcn_mfma_f32_16x16x32_bf16(ap, bv, cacc[dc], 0, 0, 0);
            }
        }
    }

    // epilogue: ctx merged [b*2048+q][h*64+d] bf16
    int bb = bh >> 4, h = bh & 15;
#pragma unroll
    for (int dc = 0; dc < 4; ++dc)
#pragma unroll
        for (int r = 0; r < 4; ++r) {
            int qg = q0 + w * 16 + ((lane >> 4) << 2) + r;
            int d = dc * 16 + (lane & 15);
            ctx[((size_t)bb * 2048 + qg) * 1024 + h * 64 + d] = (__bf16)cacc[dc][r];
        }
}

extern "C" void kernel_launch(void* const* d_in, const int* in_sizes, int n_in,
                              void* d_out, int out_size, void* d_ws, size_t ws_size,
                              hipStream_t stream) {
    const float* q  = (const float*)d_in[0];
    const float* k  = (const float*)d_in[1];
    const float* v  = (const float*)d_in[2];
    const float* Wq = (const float*)d_in[3];
    const float* bq = (const float*)d_in[4];
    const float* Wk = (const float*)d_in[5];
    const float* bk = (const float*)d_in[6];
    const float* Wv = (const float*)d_in[7];
    const float* bv = (const float*)d_in[8];
    const float* Wo = (const float*)d_in[9];
    const float* bo = (const float*)d_in[10];
    __bf16* ws = (__bf16*)d_ws;          // needs ~126 MB of scratch
    float* out  = (float*)d_out;         // [8192][1024] fp32
    float* wout = out + 8388608;         // weights [4][16][2048][2048] fp32

    convert_k<<<dim3(14336), dim3(256), 0, stream>>>(q, k, v, Wq, Wk, Wv, Wo, ws);
    gemm_k<0><<<dim3(64, 8, 3), dim3(256), 0, stream>>>(ws, bq, bk, bv, bo, out);
    attn_k<<<dim3(32, 64), dim3(256), 0, stream>>>(ws, ws, wout);
    gemm_k<1><<<dim3(64, 8, 1), dim3(256), 0, stream>>>(ws, bq, bk, bv, bo, out);
}